// Round 1
// baseline (3430.415 us; speedup 1.0000x reference)
//
#include <hip/hip_runtime.h>

#define OUTC 64

// One wave (64 lanes) per nonzero; lane = output channel.
// out[r, lane] += v * W[c, lane]   (feature SpMM: W is [IN_CH, 64])
__global__ void spmm_scatter_w(const int* __restrict__ rows,
                               const int* __restrict__ cols,
                               const float* __restrict__ vals,
                               const float* __restrict__ W,
                               float* __restrict__ out, int nnz) {
    int tid   = blockIdx.x * blockDim.x + threadIdx.x;
    int wave  = tid >> 6;
    int lane  = threadIdx.x & 63;
    int nwav  = (gridDim.x * blockDim.x) >> 6;
    for (int e = wave; e < nnz; e += nwav) {
        int r   = rows[e];
        int c   = cols[e];
        float v = vals[e];
        float w = W[(size_t)c * OUTC + lane];
        atomicAdd(&out[(size_t)r * OUTC + lane], v * w);
    }
}

// out[r, lane] += v * in[c, lane]   (adjacency SpMM: in/out are [N, 64])
__global__ void spmm_scatter_d(const int* __restrict__ rows,
                               const int* __restrict__ cols,
                               const float* __restrict__ vals,
                               const float* __restrict__ in,
                               float* __restrict__ out, int nnz) {
    int tid   = blockIdx.x * blockDim.x + threadIdx.x;
    int wave  = tid >> 6;
    int lane  = threadIdx.x & 63;
    int nwav  = (gridDim.x * blockDim.x) >> 6;
    for (int e = wave; e < nnz; e += nwav) {
        int r   = rows[e];
        int c   = cols[e];
        float v = vals[e];
        float x = in[(size_t)c * OUTC + lane];
        atomicAdd(&out[(size_t)r * OUTC + lane], v * x);
    }
}

// base = relu(base + bias), bias is [64], vectorized float4
__global__ void bias_relu(float* __restrict__ p, const float* __restrict__ bias,
                          long n4) {
    long i      = (long)blockIdx.x * blockDim.x + threadIdx.x;
    long stride = (long)gridDim.x * blockDim.x;
    for (; i < n4; i += stride) {
        float4 v = reinterpret_cast<float4*>(p)[i];
        int cb = (int)((i & 15) << 2);  // channel base within the 64-wide row
        v.x = fmaxf(v.x + bias[cb + 0], 0.f);
        v.y = fmaxf(v.y + bias[cb + 1], 0.f);
        v.z = fmaxf(v.z + bias[cb + 2], 0.f);
        v.w = fmaxf(v.w + bias[cb + 3], 0.f);
        reinterpret_cast<float4*>(p)[i] = v;
    }
}

extern "C" void kernel_launch(void* const* d_in, const int* in_sizes, int n_in,
                              void* d_out, int out_size, void* d_ws, size_t ws_size,
                              hipStream_t stream) {
    const int*   fidx = (const int*)d_in[0];    // [2, FNNZ]
    const float* fval = (const float*)d_in[1];  // [FNNZ]
    const int*   aidx = (const int*)d_in[2];    // [2, ANNZ]
    const float* aval = (const float*)d_in[3];  // [ANNZ]
    const float* W    = (const float*)d_in[4];  // [IN_CH, 64]
    const float* bias = (const float*)d_in[5];  // [1, 64]
    float* out = (float*)d_out;

    const int fnnz = in_sizes[1];
    const int annz = in_sizes[3];
    const int N    = out_size / OUTC;

    float* base = (float*)d_ws;
    float* tmp  = base + (size_t)N * OUTC;
    const size_t bytes = (size_t)N * OUTC * sizeof(float);

    const int SCAT_BLOCKS = 4096;   // 16384 waves, grid-stride over nnz
    const int EW_BLOCKS   = 2048;

    // base = feat @ W
    hipMemsetAsync(base, 0, bytes, stream);
    spmm_scatter_w<<<SCAT_BLOCKS, 256, 0, stream>>>(fidx, fidx + fnnz, fval, W,
                                                    base, fnnz);
    // base = relu(base + bias)
    bias_relu<<<EW_BLOCKS, 256, 0, stream>>>(base, bias, (long)N * OUTC / 4);

    // iter 1: tmp = A @ base
    hipMemsetAsync(tmp, 0, bytes, stream);
    spmm_scatter_d<<<SCAT_BLOCKS, 256, 0, stream>>>(aidx, aidx + annz, aval,
                                                    base, tmp, annz);
    // iter 2: base = A @ tmp
    hipMemsetAsync(base, 0, bytes, stream);
    spmm_scatter_d<<<SCAT_BLOCKS, 256, 0, stream>>>(aidx, aidx + annz, aval,
                                                    tmp, base, annz);
    // iter 3: out = A @ base
    hipMemsetAsync(out, 0, bytes, stream);
    spmm_scatter_d<<<SCAT_BLOCKS, 256, 0, stream>>>(aidx, aidx + annz, aval,
                                                    base, out, annz);
}

// Round 2
// 1671.599 us; speedup vs baseline: 2.0522x; 2.0522x over previous
//
#include <hip/hip_runtime.h>

#define OUTC 64

// ---------------- CSR build: histogram -> scan -> permute ----------------

__global__ void hist_rows(const int* __restrict__ rows, int nnz,
                          int* __restrict__ counts) {
    int i  = blockIdx.x * blockDim.x + threadIdx.x;
    int st = gridDim.x * blockDim.x;
    for (; i < nnz; i += st) atomicAdd(&counts[rows[i]], 1);
}

#define SCAN_T 1024
#define SCAN_V 4
// Single-block exclusive scan; writes rowptr[0..n] and a second copy (cursor).
__global__ void exscan_single(const int* __restrict__ in, int n,
                              int* __restrict__ rowptr, int* __restrict__ cursor) {
    __shared__ int sdata[SCAN_T];
    __shared__ int s_carry;
    if (threadIdx.x == 0) s_carry = 0;
    __syncthreads();
    const int CHUNK = SCAN_T * SCAN_V;
    for (int base = 0; base < n; base += CHUNK) {
        int idx0 = base + (int)threadIdx.x * SCAN_V;
        int v[SCAN_V];
        int sum = 0;
#pragma unroll
        for (int j = 0; j < SCAN_V; j++) {
            int i = idx0 + j;
            v[j] = (i < n) ? in[i] : 0;
            sum += v[j];
        }
        sdata[threadIdx.x] = sum;
        __syncthreads();
        for (int off = 1; off < SCAN_T; off <<= 1) {
            int t = (threadIdx.x >= (unsigned)off) ? sdata[threadIdx.x - off] : 0;
            __syncthreads();
            sdata[threadIdx.x] += t;
            __syncthreads();
        }
        int run = sdata[threadIdx.x] - sum + s_carry;  // exclusive base for this thread
#pragma unroll
        for (int j = 0; j < SCAN_V; j++) {
            int i = idx0 + j;
            if (i < n) { rowptr[i] = run; cursor[i] = run; }
            run += v[j];
        }
        __syncthreads();  // everyone done reading s_carry
        if (threadIdx.x == SCAN_T - 1) s_carry += sdata[SCAN_T - 1];
        __syncthreads();  // carry visible for next chunk
    }
    if (threadIdx.x == 0) rowptr[n] = s_carry;
}

// perm[p] = (col, bits(val)) packed, p assigned per-row via cursor atomics.
__global__ void scatter_build(const int* __restrict__ rows, const int* __restrict__ cols,
                              const float* __restrict__ vals, int nnz,
                              int* __restrict__ cursor, int2* __restrict__ perm) {
    int i  = blockIdx.x * blockDim.x + threadIdx.x;
    int st = gridDim.x * blockDim.x;
    for (; i < nnz; i += st) {
        int r = rows[i];
        int p = atomicAdd(&cursor[r], 1);
        perm[p] = make_int2(cols[i], __float_as_int(vals[i]));
    }
}

// ---------------- gather SpMM: one wave per row, lane = channel ----------------

template <bool RELU>
__global__ void spmm_gather(const int* __restrict__ rowptr, const int2* __restrict__ perm,
                            const float* __restrict__ B, const float* __restrict__ bias,
                            float* __restrict__ out, int nrows) {
    int wave = (blockIdx.x * blockDim.x + threadIdx.x) >> 6;
    int lane = threadIdx.x & 63;
    if (wave >= nrows) return;
    int s = rowptr[wave], e = rowptr[wave + 1];
    float acc = 0.f;
    int i = s;
    for (; i + 4 <= e; i += 4) {
        int2 p0 = perm[i];
        int2 p1 = perm[i + 1];
        int2 p2 = perm[i + 2];
        int2 p3 = perm[i + 3];
        float b0 = B[(size_t)p0.x * OUTC + lane];
        float b1 = B[(size_t)p1.x * OUTC + lane];
        float b2 = B[(size_t)p2.x * OUTC + lane];
        float b3 = B[(size_t)p3.x * OUTC + lane];
        acc += __int_as_float(p0.y) * b0;
        acc += __int_as_float(p1.y) * b1;
        acc += __int_as_float(p2.y) * b2;
        acc += __int_as_float(p3.y) * b3;
    }
    for (; i < e; ++i) {
        int2 p = perm[i];
        acc += __int_as_float(p.y) * B[(size_t)p.x * OUTC + lane];
    }
    if (RELU) acc = fmaxf(acc + bias[lane], 0.f);
    out[(size_t)wave * OUTC + lane] = acc;
}

// ---------------- fallback (round-1 atomic path, needs only 2 buffers) ----------------

__global__ void spmm_scatter_w(const int* __restrict__ rows, const int* __restrict__ cols,
                               const float* __restrict__ vals, const float* __restrict__ W,
                               float* __restrict__ out, int nnz) {
    int tid  = blockIdx.x * blockDim.x + threadIdx.x;
    int wave = tid >> 6;
    int lane = threadIdx.x & 63;
    int nwav = (gridDim.x * blockDim.x) >> 6;
    for (int e = wave; e < nnz; e += nwav) {
        int r = rows[e];
        int c = cols[e];
        float v = vals[e];
        atomicAdd(&out[(size_t)r * OUTC + lane], v * W[(size_t)c * OUTC + lane]);
    }
}

__global__ void bias_relu(float* __restrict__ p, const float* __restrict__ bias, long n4) {
    long i      = (long)blockIdx.x * blockDim.x + threadIdx.x;
    long stride = (long)gridDim.x * blockDim.x;
    for (; i < n4; i += stride) {
        float4 v = reinterpret_cast<float4*>(p)[i];
        int cb = (int)((i & 15) << 2);
        v.x = fmaxf(v.x + bias[cb + 0], 0.f);
        v.y = fmaxf(v.y + bias[cb + 1], 0.f);
        v.z = fmaxf(v.z + bias[cb + 2], 0.f);
        v.w = fmaxf(v.w + bias[cb + 3], 0.f);
        reinterpret_cast<float4*>(p)[i] = v;
    }
}

__global__ void spmm_scatter_d(const int* __restrict__ rows, const int* __restrict__ cols,
                               const float* __restrict__ vals, const float* __restrict__ in,
                               float* __restrict__ out, int nnz) {
    int tid  = blockIdx.x * blockDim.x + threadIdx.x;
    int wave = tid >> 6;
    int lane = threadIdx.x & 63;
    int nwav = (gridDim.x * blockDim.x) >> 6;
    for (int e = wave; e < nnz; e += nwav) {
        int r = rows[e];
        int c = cols[e];
        float v = vals[e];
        atomicAdd(&out[(size_t)r * OUTC + lane], v * in[(size_t)c * OUTC + lane]);
    }
}

// ---------------- launch ----------------

static inline size_t align256(size_t x) { return (x + 255) & ~(size_t)255; }

extern "C" void kernel_launch(void* const* d_in, const int* in_sizes, int n_in,
                              void* d_out, int out_size, void* d_ws, size_t ws_size,
                              hipStream_t stream) {
    const int*   fidx = (const int*)d_in[0];    // [2, FNNZ] rows then cols
    const float* fval = (const float*)d_in[1];  // [FNNZ]
    const int*   aidx = (const int*)d_in[2];    // [2, ANNZ]
    const float* aval = (const float*)d_in[3];  // [ANNZ]
    const float* W    = (const float*)d_in[4];  // [IN_CH, 64]
    const float* bias = (const float*)d_in[5];  // [1, 64]
    float* out = (float*)d_out;

    const int fnnz = in_sizes[1];
    const int annz = in_sizes[3];
    const int N    = out_size / OUTC;

    const size_t NB = (size_t)N * OUTC * sizeof(float);
    size_t off = 0;
    float* base = (float*)((char*)d_ws + off); off += align256(NB);
    float* tmp  = (float*)((char*)d_ws + off); off += align256(NB);
    int2*  perm = (int2*)((char*)d_ws + off);
    size_t permBytes = (size_t)(fnnz > annz ? fnnz : annz) * sizeof(int2);
    off += align256(permBytes);
    int* counts = (int*)((char*)d_ws + off); off += align256((size_t)N * 4);
    int* rowptr = (int*)((char*)d_ws + off); off += align256(((size_t)N + 1) * 4);
    int* cursor = (int*)((char*)d_ws + off); off += align256((size_t)N * 4);

    const int NZ_BLOCKS = 2048;
    const int GA_BLOCKS = (N * (OUTC / 4) + 255) / 256 * 4 / 4;  // N*64 threads / 256
    const int gatherBlocks = (N * 64 + 255) / 256;

    if (ws_size >= off) {
        // ---- feature SpMM: build CSR of feat, gather with fused bias+relu ----
        hipMemsetAsync(counts, 0, (size_t)N * 4, stream);
        hist_rows<<<NZ_BLOCKS, 256, 0, stream>>>(fidx, fnnz, counts);
        exscan_single<<<1, SCAN_T, 0, stream>>>(counts, N, rowptr, cursor);
        scatter_build<<<NZ_BLOCKS, 256, 0, stream>>>(fidx, fidx + fnnz, fval, fnnz,
                                                     cursor, perm);
        spmm_gather<true><<<gatherBlocks, 256, 0, stream>>>(rowptr, perm, W, bias,
                                                            base, N);
        // ---- adjacency CSR (built once, reused 3x) ----
        hipMemsetAsync(counts, 0, (size_t)N * 4, stream);
        hist_rows<<<NZ_BLOCKS, 256, 0, stream>>>(aidx, annz, counts);
        exscan_single<<<1, SCAN_T, 0, stream>>>(counts, N, rowptr, cursor);
        scatter_build<<<NZ_BLOCKS, 256, 0, stream>>>(aidx, aidx + annz, aval, annz,
                                                     cursor, perm);
        spmm_gather<false><<<gatherBlocks, 256, 0, stream>>>(rowptr, perm, base,
                                                             nullptr, tmp, N);
        spmm_gather<false><<<gatherBlocks, 256, 0, stream>>>(rowptr, perm, tmp,
                                                             nullptr, base, N);
        spmm_gather<false><<<gatherBlocks, 256, 0, stream>>>(rowptr, perm, base,
                                                             nullptr, out, N);
    } else {
        // ---- fallback: round-1 atomic scatter path (2 buffers only) ----
        hipMemsetAsync(base, 0, NB, stream);
        spmm_scatter_w<<<4096, 256, 0, stream>>>(fidx, fidx + fnnz, fval, W, base, fnnz);
        bias_relu<<<2048, 256, 0, stream>>>(base, bias, (long)N * OUTC / 4);
        hipMemsetAsync(tmp, 0, NB, stream);
        spmm_scatter_d<<<4096, 256, 0, stream>>>(aidx, aidx + annz, aval, base, tmp, annz);
        hipMemsetAsync(base, 0, NB, stream);
        spmm_scatter_d<<<4096, 256, 0, stream>>>(aidx, aidx + annz, aval, tmp, base, annz);
        hipMemsetAsync(out, 0, NB, stream);
        spmm_scatter_d<<<4096, 256, 0, stream>>>(aidx, aidx + annz, aval, base, out, annz);
    }
    (void)GA_BLOCKS; (void)ws_size;
}